// Round 4
// baseline (176.888 us; speedup 1.0000x reference)
//
#include <hip/hip_runtime.h>

#define BB 32
#define NN 1024
#define FIN 64
#define HH 24
#define K4C 256
#define LOG2E 1.4426950408889634f

// ---------------- kernel 1: Z = relu(xt @ W + b), plus transposed copy ----------------
__global__ void k_z(const float* __restrict__ xt, const float* __restrict__ W,
                    const float* __restrict__ bias,
                    float* __restrict__ Z, float* __restrict__ Zt) {
    __shared__ float Wl[FIN * HH];
    int t = threadIdx.x;
    for (int i = t; i < FIN * HH; i += 256) Wl[i] = W[i];
    __syncthreads();

    int row = blockIdx.x * 256 + t;      // b*N + n
    int b = row >> 10, n = row & (NN - 1);

    const float* xr = xt + (size_t)row * FIN;
    float x[FIN];
    #pragma unroll
    for (int k4 = 0; k4 < FIN / 4; ++k4) {
        float4 v = reinterpret_cast<const float4*>(xr)[k4];
        x[4 * k4 + 0] = v.x; x[4 * k4 + 1] = v.y;
        x[4 * k4 + 2] = v.z; x[4 * k4 + 3] = v.w;
    }

    float z[HH];
    #pragma unroll
    for (int hg = 0; hg < HH / 4; ++hg) {
        float4 acc = reinterpret_cast<const float4*>(bias)[hg];
        #pragma unroll
        for (int k = 0; k < FIN; ++k) {
            float4 w = *reinterpret_cast<const float4*>(&Wl[k * HH + hg * 4]);
            acc.x += x[k] * w.x; acc.y += x[k] * w.y;
            acc.z += x[k] * w.z; acc.w += x[k] * w.w;
        }
        z[hg * 4 + 0] = fmaxf(acc.x, 0.f);
        z[hg * 4 + 1] = fmaxf(acc.y, 0.f);
        z[hg * 4 + 2] = fmaxf(acc.z, 0.f);
        z[hg * 4 + 3] = fmaxf(acc.w, 0.f);
    }

    float* zr = Z + (size_t)row * HH;
    #pragma unroll
    for (int hg = 0; hg < HH / 4; ++hg)
        reinterpret_cast<float4*>(zr)[hg] =
            make_float4(z[4 * hg], z[4 * hg + 1], z[4 * hg + 2], z[4 * hg + 3]);

    #pragma unroll
    for (int h = 0; h < HH; ++h)
        Zt[((size_t)b * HH + h) * NN + n] = z[h];   // coalesced across lanes
}

// Shared structure for the three pair-sweep kernels:
//   block = 16 n-rows (4 waves x 4 rows in regs, n-side pre-scaled by log2e),
//   m swept in 4 chunks of 256 staged in LDS from Zt (coalesced b128),
//   lane-distinct ds_read_b128 (stride 16B: conflict-free).

// ---------------- kernel 2: L[n] = log2(sum_m exp2(log2e * <Zn,Zm>)) ----------------
// Z >= 0 so dots in [0,~40]: no max-subtraction needed (sum << fp32 max).
__global__ __launch_bounds__(256) void k_rowsum(
        const float* __restrict__ Z, const float* __restrict__ Zt,
        float* __restrict__ L) {
    __shared__ float Zs[HH][K4C];
    int t = threadIdx.x, lane = t & 63, w = t >> 6;
    int b = blockIdx.y;
    int n0 = blockIdx.x * 16;

    float zn[4][HH];
    #pragma unroll
    for (int r = 0; r < 4; ++r) {
        const float4* zr = reinterpret_cast<const float4*>(Z + ((size_t)b * NN + n0 + w * 4 + r) * HH);
        #pragma unroll
        for (int i = 0; i < HH / 4; ++i) {
            float4 v = zr[i];
            zn[r][4 * i + 0] = v.x * LOG2E; zn[r][4 * i + 1] = v.y * LOG2E;
            zn[r][4 * i + 2] = v.z * LOG2E; zn[r][4 * i + 3] = v.w * LOG2E;
        }
    }

    float s[4] = {0.f, 0.f, 0.f, 0.f};

    for (int mc = 0; mc < NN; mc += K4C) {
        __syncthreads();
        for (int i = t; i < HH * K4C / 4; i += 256) {
            int h = i >> 6, p = i & 63;
            reinterpret_cast<float4*>(&Zs[h][0])[p] =
                reinterpret_cast<const float4*>(Zt + ((size_t)b * HH + h) * NN + mc)[p];
        }
        __syncthreads();

        int ml = lane * 4;
        float acc[4][4];
        #pragma unroll
        for (int r = 0; r < 4; ++r)
            #pragma unroll
            for (int k = 0; k < 4; ++k) acc[r][k] = 0.f;

        #pragma unroll
        for (int h = 0; h < HH; ++h) {
            float4 zm = *reinterpret_cast<const float4*>(&Zs[h][ml]);
            #pragma unroll
            for (int r = 0; r < 4; ++r) {
                acc[r][0] += zn[r][h] * zm.x;
                acc[r][1] += zn[r][h] * zm.y;
                acc[r][2] += zn[r][h] * zm.z;
                acc[r][3] += zn[r][h] * zm.w;
            }
        }
        #pragma unroll
        for (int r = 0; r < 4; ++r)
            s[r] += __builtin_amdgcn_exp2f(acc[r][0]) + __builtin_amdgcn_exp2f(acc[r][1])
                  + __builtin_amdgcn_exp2f(acc[r][2]) + __builtin_amdgcn_exp2f(acc[r][3]);
    }

    #pragma unroll
    for (int off = 1; off < 64; off <<= 1)
        #pragma unroll
        for (int r = 0; r < 4; ++r)
            s[r] += __shfl_xor(s[r], off, 64);

    if (lane == 0) {
        #pragma unroll
        for (int r = 0; r < 4; ++r)
            L[(size_t)b * NN + n0 + w * 4 + r] = __builtin_amdgcn_logf(s[r]);
    }
}

// ---------------- kernel 3: colsum of S -> dinv ----------------
// c[n] = sum_m exp2(log2e*a(n,m) - L[m]);  dinv = rsqrt(1.5 + 0.5 c)
__global__ __launch_bounds__(256) void k_colsum(
        const float* __restrict__ Z, const float* __restrict__ Zt,
        const float* __restrict__ L, float* __restrict__ dinv) {
    __shared__ float Zs[HH][K4C];
    __shared__ float lS[K4C];
    int t = threadIdx.x, lane = t & 63, w = t >> 6;
    int b = blockIdx.y;
    int n0 = blockIdx.x * 16;

    float zn[4][HH];
    #pragma unroll
    for (int r = 0; r < 4; ++r) {
        const float4* zr = reinterpret_cast<const float4*>(Z + ((size_t)b * NN + n0 + w * 4 + r) * HH);
        #pragma unroll
        for (int i = 0; i < HH / 4; ++i) {
            float4 v = zr[i];
            zn[r][4 * i + 0] = v.x * LOG2E; zn[r][4 * i + 1] = v.y * LOG2E;
            zn[r][4 * i + 2] = v.z * LOG2E; zn[r][4 * i + 3] = v.w * LOG2E;
        }
    }

    float c[4] = {0.f, 0.f, 0.f, 0.f};

    for (int mc = 0; mc < NN; mc += K4C) {
        __syncthreads();
        for (int i = t; i < HH * K4C / 4; i += 256) {
            int h = i >> 6, p = i & 63;
            reinterpret_cast<float4*>(&Zs[h][0])[p] =
                reinterpret_cast<const float4*>(Zt + ((size_t)b * HH + h) * NN + mc)[p];
        }
        lS[t] = L[(size_t)b * NN + mc + t];
        __syncthreads();

        int ml = lane * 4;
        float acc[4][4];
        #pragma unroll
        for (int r = 0; r < 4; ++r)
            #pragma unroll
            for (int k = 0; k < 4; ++k) acc[r][k] = 0.f;

        #pragma unroll
        for (int h = 0; h < HH; ++h) {
            float4 zm = *reinterpret_cast<const float4*>(&Zs[h][ml]);
            #pragma unroll
            for (int r = 0; r < 4; ++r) {
                acc[r][0] += zn[r][h] * zm.x;
                acc[r][1] += zn[r][h] * zm.y;
                acc[r][2] += zn[r][h] * zm.z;
                acc[r][3] += zn[r][h] * zm.w;
            }
        }
        float4 l4 = *reinterpret_cast<const float4*>(&lS[ml]);
        #pragma unroll
        for (int r = 0; r < 4; ++r)
            c[r] += __builtin_amdgcn_exp2f(acc[r][0] - l4.x) + __builtin_amdgcn_exp2f(acc[r][1] - l4.y)
                  + __builtin_amdgcn_exp2f(acc[r][2] - l4.z) + __builtin_amdgcn_exp2f(acc[r][3] - l4.w);
    }

    #pragma unroll
    for (int off = 1; off < 64; off <<= 1)
        #pragma unroll
        for (int r = 0; r < 4; ++r)
            c[r] += __shfl_xor(c[r], off, 64);

    if (lane == 0) {
        #pragma unroll
        for (int r = 0; r < 4; ++r)
            dinv[(size_t)b * NN + n0 + w * 4 + r] = rsqrtf(1.5f + 0.5f * c[r]);
    }
}

// ---------------- kernel 4: final output ----------------
// out[n,m] = (exp2(â - Ln - 1) + exp2(â - Lm - 1) + diag) * dvn * dvm
__global__ __launch_bounds__(256) void k_out(
    const float* __restrict__ Z, const float* __restrict__ Zt,
    const float* __restrict__ L, const float* __restrict__ dinv,
    float* __restrict__ out) {
    __shared__ float Zs[HH][K4C];
    __shared__ float lS[K4C], dvS[K4C];

    int t = threadIdx.x, lane = t & 63, w = t >> 6;
    int b = blockIdx.y;
    int n0 = blockIdx.x * 16;

    float zn[4][HH];
    float lse_n[4], dv_n[4];
    int nrow[4];
    #pragma unroll
    for (int r = 0; r < 4; ++r) {
        int n = n0 + w * 4 + r;
        nrow[r] = n;
        const float* zr = Z + ((size_t)b * NN + n) * HH;
        #pragma unroll
        for (int i = 0; i < HH / 4; ++i) {
            float4 v = reinterpret_cast<const float4*>(zr)[i];
            zn[r][4 * i + 0] = v.x * LOG2E; zn[r][4 * i + 1] = v.y * LOG2E;
            zn[r][4 * i + 2] = v.z * LOG2E; zn[r][4 * i + 3] = v.w * LOG2E;
        }
        lse_n[r] = L[(size_t)b * NN + n] + 1.0f;   // +1 folds the 0.5
        dv_n[r]  = dinv[(size_t)b * NN + n];
    }

    for (int mc = 0; mc < NN; mc += K4C) {
        __syncthreads();
        for (int i = t; i < HH * K4C / 4; i += 256) {
            int h = i >> 6, p = i & 63;
            reinterpret_cast<float4*>(&Zs[h][0])[p] =
                reinterpret_cast<const float4*>(Zt + ((size_t)b * HH + h) * NN + mc)[p];
        }
        lS[t]  = L[(size_t)b * NN + mc + t] + 1.0f;
        dvS[t] = dinv[(size_t)b * NN + mc + t];
        __syncthreads();

        int ml = lane * 4;
        int m0 = mc + ml;
        float4 lse4 = *reinterpret_cast<const float4*>(&lS[ml]);
        float4 dv4  = *reinterpret_cast<const float4*>(&dvS[ml]);

        float acc[4][4];
        #pragma unroll
        for (int r = 0; r < 4; ++r)
            #pragma unroll
            for (int k = 0; k < 4; ++k) acc[r][k] = 0.f;

        #pragma unroll
        for (int h = 0; h < HH; ++h) {
            float4 zm = *reinterpret_cast<const float4*>(&Zs[h][ml]);
            #pragma unroll
            for (int r = 0; r < 4; ++r) {
                acc[r][0] += zn[r][h] * zm.x;
                acc[r][1] += zn[r][h] * zm.y;
                acc[r][2] += zn[r][h] * zm.z;
                acc[r][3] += zn[r][h] * zm.w;
            }
        }

        #pragma unroll
        for (int r = 0; r < 4; ++r) {
            float ln = lse_n[r], dn = dv_n[r];
            float4 o;
            o.x = __builtin_amdgcn_exp2f(acc[r][0] - ln) + __builtin_amdgcn_exp2f(acc[r][0] - lse4.x);
            o.y = __builtin_amdgcn_exp2f(acc[r][1] - ln) + __builtin_amdgcn_exp2f(acc[r][1] - lse4.y);
            o.z = __builtin_amdgcn_exp2f(acc[r][2] - ln) + __builtin_amdgcn_exp2f(acc[r][2] - lse4.z);
            o.w = __builtin_amdgcn_exp2f(acc[r][3] - ln) + __builtin_amdgcn_exp2f(acc[r][3] - lse4.w);
            if (nrow[r] == m0 + 0) o.x += 1.0f;
            if (nrow[r] == m0 + 1) o.y += 1.0f;
            if (nrow[r] == m0 + 2) o.z += 1.0f;
            if (nrow[r] == m0 + 3) o.w += 1.0f;
            o.x *= dn * dv4.x;
            o.y *= dn * dv4.y;
            o.z *= dn * dv4.z;
            o.w *= dn * dv4.w;
            *reinterpret_cast<float4*>(&out[((size_t)b * NN + nrow[r]) * NN + m0]) = o;
        }
    }
}

extern "C" void kernel_launch(void* const* d_in, const int* in_sizes, int n_in,
                              void* d_out, int out_size, void* d_ws, size_t ws_size,
                              hipStream_t stream) {
    const float* xt   = (const float*)d_in[0];
    const float* W    = (const float*)d_in[1];
    const float* bias = (const float*)d_in[2];
    float* out = (float*)d_out;
    float* ws  = (float*)d_ws;

    const size_t Z_OFF  = 0;
    const size_t ZT_OFF = Z_OFF  + (size_t)BB * NN * HH;
    const size_t LS_OFF = ZT_OFF + (size_t)BB * HH * NN;
    const size_t DV_OFF = LS_OFF + (size_t)BB * NN;

    float* Z    = ws + Z_OFF;
    float* Zt   = ws + ZT_OFF;
    float* L    = ws + LS_OFF;
    float* dinv = ws + DV_OFF;

    k_z<<<dim3(BB * NN / 256), dim3(256), 0, stream>>>(xt, W, bias, Z, Zt);
    k_rowsum<<<dim3(NN / 16, BB), dim3(256), 0, stream>>>(Z, Zt, L);
    k_colsum<<<dim3(NN / 16, BB), dim3(256), 0, stream>>>(Z, Zt, L, dinv);
    k_out<<<dim3(NN / 16, BB), dim3(256), 0, stream>>>(Z, Zt, L, dinv, out);
}

// Round 5
// 87.500 us; speedup vs baseline: 2.0216x; 2.0216x over previous
//
#include <hip/hip_runtime.h>

#define BB 32
#define NN 1024
#define FIN 64
#define HH 24
// sqrt(log2(e)): scores computed as sum of (z*s)^2-style products are in log2 domain
#define SQRT_LOG2E 1.2011224087864498f

typedef __attribute__((ext_vector_type(8))) short short8;
typedef __attribute__((ext_vector_type(4))) float floatx4;

static __device__ inline unsigned short bf16_rtne(float f) {
    unsigned u = __float_as_uint(f);
    unsigned r = u + 0x7FFFu + ((u >> 16) & 1u);
    return (unsigned short)(r >> 16);
}

// ---------------- kernel 1: Z = relu(xt@W+b) * SQRT_LOG2E, split hi/lo bf16 ----------------
// Zhl[b][n] = 64 ushorts: [0..23] hi bf16, [24..31] 0, [32..55] lo bf16, [56..63] 0
__global__ void k_z(const float* __restrict__ xt, const float* __restrict__ W,
                    const float* __restrict__ bias, unsigned short* __restrict__ Zhl) {
    __shared__ float Wl[FIN * HH];
    int t = threadIdx.x;
    for (int i = t; i < FIN * HH; i += 256) Wl[i] = W[i];
    __syncthreads();

    int row = blockIdx.x * 256 + t;      // b*N + n

    const float* xr = xt + (size_t)row * FIN;
    float x[FIN];
    #pragma unroll
    for (int k4 = 0; k4 < FIN / 4; ++k4) {
        float4 v = reinterpret_cast<const float4*>(xr)[k4];
        x[4 * k4 + 0] = v.x; x[4 * k4 + 1] = v.y;
        x[4 * k4 + 2] = v.z; x[4 * k4 + 3] = v.w;
    }

    unsigned short u[64];
    #pragma unroll
    for (int i = 0; i < 64; ++i) u[i] = 0;

    #pragma unroll
    for (int hg = 0; hg < HH / 4; ++hg) {
        float4 acc = reinterpret_cast<const float4*>(bias)[hg];
        #pragma unroll
        for (int k = 0; k < FIN; ++k) {
            float4 w = *reinterpret_cast<const float4*>(&Wl[k * HH + hg * 4]);
            acc.x += x[k] * w.x; acc.y += x[k] * w.y;
            acc.z += x[k] * w.z; acc.w += x[k] * w.w;
        }
        float zs[4] = { fmaxf(acc.x, 0.f) * SQRT_LOG2E, fmaxf(acc.y, 0.f) * SQRT_LOG2E,
                        fmaxf(acc.z, 0.f) * SQRT_LOG2E, fmaxf(acc.w, 0.f) * SQRT_LOG2E };
        #pragma unroll
        for (int j = 0; j < 4; ++j) {
            int h = hg * 4 + j;
            unsigned short hb = bf16_rtne(zs[j]);
            float hf = __uint_as_float((unsigned)hb << 16);
            u[h] = hb;
            u[32 + h] = bf16_rtne(zs[j] - hf);
        }
    }

    unsigned short* dst = Zhl + ((size_t)row << 6);
    #pragma unroll
    for (int i = 0; i < 8; ++i)
        reinterpret_cast<uint4*>(dst)[i] = *reinterpret_cast<const uint4*>(&u[i * 8]);
}

// Common geometry for pair-sweep kernels:
//  grid (16 n-blocks, 4 m-splits, 32 b); block 256 = 4 waves; wave w owns 16 n-rows.
//  m-window = 256 rows, staged in LDS as 2 chunks of 128 rows x 128B (hi+lo),
//  LDS layout: 16B unit (c=0..7) at offset ((c*128 + (row^c))*8) ushorts  (2-way banks max).
//  MFMA 16x16x32 bf16, 3x (hi*hi, hi*lo, lo*hi). C: row=(lane>>4)*4+reg, col=lane&15.

#define STAGE_CHUNK(m0)                                                                  \
    for (int i = t; i < 1024; i += 256) {                                                \
        int row_ = i >> 3, c_ = i & 7;                                                   \
        uint4 v_ = *reinterpret_cast<const uint4*>(                                      \
            Zhl + (((size_t)b * NN + (m0) + row_) << 6) + (c_ << 3));                    \
        *reinterpret_cast<uint4*>(&Bs[(((c_ << 7) + (row_ ^ c_)) << 3)]) = v_;           \
    }

#define LOAD_A_FRAGS()                                                                   \
    const unsigned short* arow_ = Zhl + (((size_t)b * NN + n0w + r15) << 6) + (g << 3);  \
    short8 ah = *reinterpret_cast<const short8*>(arow_);                                 \
    short8 al = *reinterpret_cast<const short8*>(arow_ + 32);

#define B_FRAGS(mt)                                                                      \
    int roff = (mt) * 16 + r15;                                                          \
    short8 bh = *reinterpret_cast<const short8*>(&Bs[((g << 7) + (roff ^ g)) << 3]);     \
    short8 bl = *reinterpret_cast<const short8*>(                                        \
        &Bs[(((g + 4) << 7) + (roff ^ (g + 4))) << 3]);                                  \
    floatx4 acc = {0.f, 0.f, 0.f, 0.f};                                                  \
    acc = __builtin_amdgcn_mfma_f32_16x16x32_bf16(ah, bh, acc, 0, 0, 0);                 \
    acc = __builtin_amdgcn_mfma_f32_16x16x32_bf16(ah, bl, acc, 0, 0, 0);                 \
    acc = __builtin_amdgcn_mfma_f32_16x16x32_bf16(al, bh, acc, 0, 0, 0);

// ---------------- kernel 2: partial row sums  ps[ms][b][n] = sum_{m in window} exp2(a) ----
__global__ __launch_bounds__(256) void k_rowsum(
        const unsigned short* __restrict__ Zhl, float* __restrict__ ps) {
    __shared__ unsigned short Bs[128 * 64];
    int t = threadIdx.x, lane = t & 63, w = t >> 6;
    int r15 = lane & 15, g = lane >> 4;
    int b = blockIdx.z;
    int n0w = blockIdx.x * 64 + w * 16;
    int mbase = blockIdx.y * 256;

    LOAD_A_FRAGS();

    float s[4] = {0.f, 0.f, 0.f, 0.f};

    #pragma unroll
    for (int ch = 0; ch < 2; ++ch) {
        __syncthreads();
        STAGE_CHUNK(mbase + ch * 128);
        __syncthreads();
        #pragma unroll
        for (int mt = 0; mt < 8; ++mt) {
            B_FRAGS(mt);
            s[0] += __builtin_amdgcn_exp2f(acc[0]);
            s[1] += __builtin_amdgcn_exp2f(acc[1]);
            s[2] += __builtin_amdgcn_exp2f(acc[2]);
            s[3] += __builtin_amdgcn_exp2f(acc[3]);
        }
    }

    #pragma unroll
    for (int off = 1; off < 16; off <<= 1)
        #pragma unroll
        for (int k = 0; k < 4; ++k) s[k] += __shfl_xor(s[k], off, 64);

    if (r15 == 0) {
        size_t base = ((size_t)blockIdx.y * BB + b) * NN + n0w + g * 4;
        #pragma unroll
        for (int k = 0; k < 4; ++k) ps[base + k] = s[k];
    }
}

// ---------------- kernel 2b: L = log2(sum of partials) ----------------
__global__ void k_rowfin(const float* __restrict__ ps, float* __restrict__ L) {
    int i = blockIdx.x * 256 + threadIdx.x;
    float s = ps[i] + ps[32768 + i] + ps[65536 + i] + ps[98304 + i];
    L[i] = __builtin_amdgcn_logf(s);
}

// ---------------- kernel 3: partial col sums of S ----------------
__global__ __launch_bounds__(256) void k_colsum(
        const unsigned short* __restrict__ Zhl, const float* __restrict__ L,
        float* __restrict__ pc) {
    __shared__ unsigned short Bs[128 * 64];
    __shared__ float Ls[128];
    int t = threadIdx.x, lane = t & 63, w = t >> 6;
    int r15 = lane & 15, g = lane >> 4;
    int b = blockIdx.z;
    int n0w = blockIdx.x * 64 + w * 16;
    int mbase = blockIdx.y * 256;

    LOAD_A_FRAGS();

    float s[4] = {0.f, 0.f, 0.f, 0.f};

    #pragma unroll
    for (int ch = 0; ch < 2; ++ch) {
        int m0 = mbase + ch * 128;
        __syncthreads();
        STAGE_CHUNK(m0);
        if (t < 128) Ls[t] = L[(size_t)b * NN + m0 + t];
        __syncthreads();
        #pragma unroll
        for (int mt = 0; mt < 8; ++mt) {
            B_FRAGS(mt);
            float lm = Ls[roff];
            s[0] += __builtin_amdgcn_exp2f(acc[0] - lm);
            s[1] += __builtin_amdgcn_exp2f(acc[1] - lm);
            s[2] += __builtin_amdgcn_exp2f(acc[2] - lm);
            s[3] += __builtin_amdgcn_exp2f(acc[3] - lm);
        }
    }

    #pragma unroll
    for (int off = 1; off < 16; off <<= 1)
        #pragma unroll
        for (int k = 0; k < 4; ++k) s[k] += __shfl_xor(s[k], off, 64);

    if (r15 == 0) {
        size_t base = ((size_t)blockIdx.y * BB + b) * NN + n0w + g * 4;
        #pragma unroll
        for (int k = 0; k < 4; ++k) pc[base + k] = s[k];
    }
}

// ---------------- kernel 3b: dinv = rsqrt(1.5 + 0.5 * colsum) ----------------
__global__ void k_colfin(const float* __restrict__ pc, float* __restrict__ dinv) {
    int i = blockIdx.x * 256 + threadIdx.x;
    float s = pc[i] + pc[32768 + i] + pc[65536 + i] + pc[98304 + i];
    dinv[i] = rsqrtf(1.5f + 0.5f * s);
}

// ---------------- kernel 4: out = (exp2(a)*(en+em) + diag) * dvn * dvm ----------------
__global__ __launch_bounds__(256) void k_out(
        const unsigned short* __restrict__ Zhl, const float* __restrict__ L,
        const float* __restrict__ dinv, float* __restrict__ out) {
    __shared__ unsigned short Bs[128 * 64];
    __shared__ float Ls[128], dvS[128];
    int t = threadIdx.x, lane = t & 63, w = t >> 6;
    int r15 = lane & 15, g = lane >> 4;
    int b = blockIdx.z;
    int n0w = blockIdx.x * 64 + w * 16;
    int mbase = blockIdx.y * 256;

    LOAD_A_FRAGS();

    float en4[4], dvn4[4];
    #pragma unroll
    for (int k = 0; k < 4; ++k) {
        int n = n0w + g * 4 + k;
        en4[k]  = __builtin_amdgcn_exp2f(-1.0f - L[(size_t)b * NN + n]);
        dvn4[k] = dinv[(size_t)b * NN + n];
    }

    #pragma unroll
    for (int ch = 0; ch < 2; ++ch) {
        int m0 = mbase + ch * 128;
        __syncthreads();
        STAGE_CHUNK(m0);
        if (t < 128) {
            Ls[t]  = L[(size_t)b * NN + m0 + t];
            dvS[t] = dinv[(size_t)b * NN + m0 + t];
        }
        __syncthreads();
        #pragma unroll
        for (int mt = 0; mt < 8; ++mt) {
            B_FRAGS(mt);
            float em  = __builtin_amdgcn_exp2f(-1.0f - Ls[roff]);
            float dvm = dvS[roff];
            int mg = m0 + roff;
            #pragma unroll
            for (int k = 0; k < 4; ++k) {
                int ng = n0w + g * 4 + k;
                float v = __builtin_amdgcn_exp2f(acc[k]) * (en4[k] + em);
                if (ng == mg) v += 1.0f;
                out[((size_t)b * NN + ng) * NN + mg] = v * dvn4[k] * dvm;
            }
        }
    }
}

extern "C" void kernel_launch(void* const* d_in, const int* in_sizes, int n_in,
                              void* d_out, int out_size, void* d_ws, size_t ws_size,
                              hipStream_t stream) {
    const float* xt   = (const float*)d_in[0];
    const float* W    = (const float*)d_in[1];
    const float* bias = (const float*)d_in[2];
    float* out = (float*)d_out;
    float* ws  = (float*)d_ws;

    // ws layout (float units)
    unsigned short* Zhl = (unsigned short*)ws;                  // 32*1024*64 u16 = 1,048,576 f
    float* L    = ws + 1048576;                                 // 32768
    float* dinv = ws + 1048576 + 32768;                         // 32768
    float* ps   = ws + 1048576 + 65536;                         // 4*32768 = 131072
    float* pc   = ws + 1048576 + 65536 + 131072;                // 131072

    k_z<<<dim3(BB * NN / 256), dim3(256), 0, stream>>>(xt, W, bias, Zhl);
    k_rowsum<<<dim3(16, 4, BB), dim3(256), 0, stream>>>(Zhl, ps);
    k_rowfin<<<dim3(128), dim3(256), 0, stream>>>(ps, L);
    k_colsum<<<dim3(16, 4, BB), dim3(256), 0, stream>>>(Zhl, L, pc);
    k_colfin<<<dim3(128), dim3(256), 0, stream>>>(pc, dinv);
    k_out<<<dim3(16, 4, BB), dim3(256), 0, stream>>>(Zhl, L, dinv, out);
}

// Round 7
// 83.099 us; speedup vs baseline: 2.1286x; 1.0530x over previous
//
#include <hip/hip_runtime.h>

#define BB 32
#define NN 1024
#define FIN 64
#define HH 24
#define SQRT_LOG2E 1.2011224087864498f

typedef __attribute__((ext_vector_type(8))) short short8;
typedef __attribute__((ext_vector_type(4))) float floatx4;

static __device__ inline unsigned short bf16_rtne(float f) {
    unsigned u = __float_as_uint(f);
    unsigned r = u + 0x7FFFu + ((u >> 16) & 1u);
    return (unsigned short)(r >> 16);
}

// ---------------- kernel 1: Z = relu(xt@W+b) * SQRT_LOG2E, split hi/lo bf16 ----------------
// Zhl[b][n] = 64 ushorts: [0..23] hi bf16, [24..31] 0, [32..55] lo bf16, [56..63] 0
__global__ void k_z(const float* __restrict__ xt, const float* __restrict__ W,
                    const float* __restrict__ bias, unsigned short* __restrict__ Zhl) {
    __shared__ float Wl[FIN * HH];
    int t = threadIdx.x;
    for (int i = t; i < FIN * HH; i += 256) Wl[i] = W[i];
    __syncthreads();

    int row = blockIdx.x * 256 + t;      // b*N + n

    const float* xr = xt + (size_t)row * FIN;
    float x[FIN];
    #pragma unroll
    for (int k4 = 0; k4 < FIN / 4; ++k4) {
        float4 v = reinterpret_cast<const float4*>(xr)[k4];
        x[4 * k4 + 0] = v.x; x[4 * k4 + 1] = v.y;
        x[4 * k4 + 2] = v.z; x[4 * k4 + 3] = v.w;
    }

    unsigned short u[64];
    #pragma unroll
    for (int i = 0; i < 64; ++i) u[i] = 0;

    #pragma unroll
    for (int hg = 0; hg < HH / 4; ++hg) {
        float4 acc = reinterpret_cast<const float4*>(bias)[hg];
        #pragma unroll
        for (int k = 0; k < FIN; ++k) {
            float4 w = *reinterpret_cast<const float4*>(&Wl[k * HH + hg * 4]);
            acc.x += x[k] * w.x; acc.y += x[k] * w.y;
            acc.z += x[k] * w.z; acc.w += x[k] * w.w;
        }
        float zs[4] = { fmaxf(acc.x, 0.f) * SQRT_LOG2E, fmaxf(acc.y, 0.f) * SQRT_LOG2E,
                        fmaxf(acc.z, 0.f) * SQRT_LOG2E, fmaxf(acc.w, 0.f) * SQRT_LOG2E };
        #pragma unroll
        for (int j = 0; j < 4; ++j) {
            int h = hg * 4 + j;
            unsigned short hb = bf16_rtne(zs[j]);
            float hf = __uint_as_float((unsigned)hb << 16);
            u[h] = hb;
            u[32 + h] = bf16_rtne(zs[j] - hf);
        }
    }

    unsigned short* dst = Zhl + ((size_t)row << 6);
    #pragma unroll
    for (int i = 0; i < 8; ++i)
        reinterpret_cast<uint4*>(dst)[i] = *reinterpret_cast<const uint4*>(&u[i * 8]);
}

// Common geometry (all pair-sweep kernels):
//  grid (16 n-blocks, 4 m-splits, 32 b); block 256 = 4 waves; wave owns 16 n (B operand, regs);
//  m-window 256 = 2 LDS chunks of 128 rows x 128B (hi+lo), swizzled (c*128 + (row^c)) -> 2-way max.
//  MFMA 16x16x32 bf16, A = m-tile (LDS), B = n-frag (regs), 3x: mh*nh + mh*nl + ml*nh.
//  C layout: lane holds n = n0w + (lane&15), m = mt*16 + (lane>>4)*4 + k  (4 consecutive m!).

#define STAGE_CHUNK(m0)                                                                  \
    for (int i = t; i < 1024; i += 256) {                                                \
        int row_ = i >> 3, c_ = i & 7;                                                   \
        uint4 v_ = *reinterpret_cast<const uint4*>(                                      \
            Zhl + (((size_t)b * NN + (m0) + row_) << 6) + (c_ << 3));                    \
        *reinterpret_cast<uint4*>(&Bs[(((c_ << 7) + (row_ ^ c_)) << 3)]) = v_;           \
    }

#define LOAD_N_FRAGS()                                                                   \
    const unsigned short* nrow_ = Zhl + (((size_t)b * NN + n0w + r15) << 6) + (g << 3);  \
    short8 nh = *reinterpret_cast<const short8*>(nrow_);                                 \
    short8 nl = *reinterpret_cast<const short8*>(nrow_ + 32);

#define MFMA_TILE(mt)                                                                    \
    int roff = (mt) * 16 + r15;                                                          \
    short8 mh = *reinterpret_cast<const short8*>(&Bs[((g << 7) + (roff ^ g)) << 3]);     \
    short8 ml = *reinterpret_cast<const short8*>(                                        \
        &Bs[(((g + 4) << 7) + (roff ^ (g + 4))) << 3]);                                  \
    floatx4 acc = {0.f, 0.f, 0.f, 0.f};                                                  \
    acc = __builtin_amdgcn_mfma_f32_16x16x32_bf16(mh, nh, acc, 0, 0, 0);                 \
    acc = __builtin_amdgcn_mfma_f32_16x16x32_bf16(mh, nl, acc, 0, 0, 0);                 \
    acc = __builtin_amdgcn_mfma_f32_16x16x32_bf16(ml, nh, acc, 0, 0, 0);

// ---------------- kernel 2: partial row sums  ps[ms][b][n] = sum_{m in window} exp2(a) ----
__global__ __launch_bounds__(256) void k_rowsum(
        const unsigned short* __restrict__ Zhl, float* __restrict__ ps) {
    __shared__ unsigned short Bs[128 * 64];
    int t = threadIdx.x, lane = t & 63;
    int r15 = lane & 15, g = lane >> 4;
    int b = blockIdx.z;
    int n0w = blockIdx.x * 64 + (t >> 6) * 16;
    int mbase = blockIdx.y * 256;

    LOAD_N_FRAGS();

    float s = 0.f;

    #pragma unroll
    for (int ch = 0; ch < 2; ++ch) {
        __syncthreads();
        STAGE_CHUNK(mbase + ch * 128);
        __syncthreads();
        #pragma unroll
        for (int mt = 0; mt < 8; ++mt) {
            MFMA_TILE(mt);
            s += __builtin_amdgcn_exp2f(acc[0]) + __builtin_amdgcn_exp2f(acc[1])
               + __builtin_amdgcn_exp2f(acc[2]) + __builtin_amdgcn_exp2f(acc[3]);
        }
    }

    s += __shfl_xor(s, 16, 64);
    s += __shfl_xor(s, 32, 64);
    if (g == 0)
        ps[((size_t)blockIdx.y * BB + b) * NN + n0w + r15] = s;
}

// ---------------- kernel 3: partial col sums  pc[ms][b][n] = sum_m exp2(a)/s_m ----------
__global__ __launch_bounds__(256) void k_colsum(
        const unsigned short* __restrict__ Zhl, const float* __restrict__ ps,
        float* __restrict__ pc) {
    __shared__ unsigned short Bs[128 * 64];
    __shared__ float rmS[256];
    int t = threadIdx.x, lane = t & 63;
    int r15 = lane & 15, g = lane >> 4;
    int b = blockIdx.z;
    int n0w = blockIdx.x * 64 + (t >> 6) * 16;
    int mbase = blockIdx.y * 256;

    // 1/s_m for the whole m-window
    {
        size_t o = (size_t)b * NN + mbase + t;
        float sm = ps[o] + ps[32768 + o] + ps[65536 + o] + ps[98304 + o];
        rmS[t] = 1.0f / sm;
    }

    LOAD_N_FRAGS();

    float c = 0.f;

    #pragma unroll
    for (int ch = 0; ch < 2; ++ch) {
        __syncthreads();
        STAGE_CHUNK(mbase + ch * 128);
        __syncthreads();
        #pragma unroll
        for (int mt = 0; mt < 8; ++mt) {
            MFMA_TILE(mt);
            float4 rm4 = *reinterpret_cast<const float4*>(&rmS[ch * 128 + mt * 16 + g * 4]);
            c += __builtin_amdgcn_exp2f(acc[0]) * rm4.x + __builtin_amdgcn_exp2f(acc[1]) * rm4.y
               + __builtin_amdgcn_exp2f(acc[2]) * rm4.z + __builtin_amdgcn_exp2f(acc[3]) * rm4.w;
        }
    }

    c += __shfl_xor(c, 16, 64);
    c += __shfl_xor(c, 32, 64);
    if (g == 0)
        pc[((size_t)blockIdx.y * BB + b) * NN + n0w + r15] = c;
}

// ---------------- kernel 4: out = (exp2(a)*(0.5/sn + 0.5/sm) + diag) * dvn * dvm ---------
__global__ __launch_bounds__(256) void k_out(
        const unsigned short* __restrict__ Zhl, const float* __restrict__ ps,
        const float* __restrict__ pc, float* __restrict__ out) {
    __shared__ unsigned short Bs[128 * 64];
    __shared__ float emS[256], dvmS[256];
    int t = threadIdx.x, lane = t & 63;
    int r15 = lane & 15, g = lane >> 4;
    int b = blockIdx.z;
    int n0w = blockIdx.x * 64 + (t >> 6) * 16;
    int mbase = blockIdx.y * 256;

    // per-m stats for the window: em = 0.5/s_m, dvm = rsqrt(1.5 + 0.5*colsum_m)
    {
        size_t o = (size_t)b * NN + mbase + t;
        float sm = ps[o] + ps[32768 + o] + ps[65536 + o] + ps[98304 + o];
        float cm = pc[o] + pc[32768 + o] + pc[65536 + o] + pc[98304 + o];
        emS[t]  = 0.5f / sm;
        dvmS[t] = rsqrtf(1.5f + 0.5f * cm);
    }

    // per-lane n stats
    int n = n0w + r15;
    float en, dvn;
    {
        size_t o = (size_t)b * NN + n;
        float sn = ps[o] + ps[32768 + o] + ps[65536 + o] + ps[98304 + o];
        float cn = pc[o] + pc[32768 + o] + pc[65536 + o] + pc[98304 + o];
        en  = 0.5f / sn;
        dvn = rsqrtf(1.5f + 0.5f * cn);
    }

    LOAD_N_FRAGS();

    float* orow = out + ((size_t)b * NN + n) * NN;

    #pragma unroll
    for (int ch = 0; ch < 2; ++ch) {
        int m0 = mbase + ch * 128;
        __syncthreads();
        STAGE_CHUNK(m0);
        __syncthreads();
        #pragma unroll
        for (int mt = 0; mt < 8; ++mt) {
            MFMA_TILE(mt);
            int mq = ch * 128 + mt * 16 + g * 4;      // window-relative m of acc[0]
            float4 em4 = *reinterpret_cast<const float4*>(&emS[mq]);
            float4 dv4 = *reinterpret_cast<const float4*>(&dvmS[mq]);
            int mg = mbase + mq;                      // global m of acc[0]
            float4 o;
            float w0 = dvn * dv4.x, w1 = dvn * dv4.y, w2 = dvn * dv4.z, w3 = dvn * dv4.w;
            o.x = __builtin_amdgcn_exp2f(acc[0]) * (en + em4.x) * w0;
            o.y = __builtin_amdgcn_exp2f(acc[1]) * (en + em4.y) * w1;
            o.z = __builtin_amdgcn_exp2f(acc[2]) * (en + em4.z) * w2;
            o.w = __builtin_amdgcn_exp2f(acc[3]) * (en + em4.w) * w3;
            if (n == mg + 0) o.x += w0;
            if (n == mg + 1) o.y += w1;
            if (n == mg + 2) o.z += w2;
            if (n == mg + 3) o.w += w3;
            *reinterpret_cast<float4*>(orow + mg) = o;
        }
    }
}

extern "C" void kernel_launch(void* const* d_in, const int* in_sizes, int n_in,
                              void* d_out, int out_size, void* d_ws, size_t ws_size,
                              hipStream_t stream) {
    const float* xt   = (const float*)d_in[0];
    const float* W    = (const float*)d_in[1];
    const float* bias = (const float*)d_in[2];
    float* out = (float*)d_out;
    float* ws  = (float*)d_ws;

    unsigned short* Zhl = (unsigned short*)ws;          // 32*1024*64 u16 = 1,048,576 floats
    float* ps = ws + 1048576;                           // [4][32][1024] = 131072
    float* pc = ws + 1048576 + 131072;                  // [4][32][1024] = 131072

    k_z<<<dim3(BB * NN / 256), dim3(256), 0, stream>>>(xt, W, bias, Zhl);
    k_rowsum<<<dim3(16, 4, BB), dim3(256), 0, stream>>>(Zhl, ps);
    k_colsum<<<dim3(16, 4, BB), dim3(256), 0, stream>>>(Zhl, ps, pc);
    k_out<<<dim3(16, 4, BB), dim3(256), 0, stream>>>(Zhl, ps, pc, out);
}